// Round 14
// baseline (1393.589 us; speedup 1.0000x reference)
//
#include <hip/hip_runtime.h>

typedef unsigned int u32;
typedef unsigned short u16;
typedef __fp16 h8 __attribute__((ext_vector_type(8)));
typedef float f32x4 __attribute__((ext_vector_type(4)));

#define BG 64
#define NNODE 320
#define NEDGE 1280
#define TT 256
#define FN 64
#define FG 16
#define HM 128
#define HU 128
#define HG 64
#define HA 4
#define ZM 512
#define ZU 512
#define ZG 256
#define ZA 16
#define DM 144
#define DU 208
#define DG 144
#define DA 192

// ---- conversion-area layout (floats, relative to ws+64) ----
#define CV 64
#define O_NODES 0
#define O_GA    20480
#define O_WM    21504
#define O_WHM   95232
#define O_BM    160768
#define O_WU    161280
#define O_WHU   267776
#define O_BU    333312
#define O_WG    333824
#define O_WHG   370688
#define O_BG2   387072
#define O_WA    387328
#define O_WHA   390400
#define O_BA    390464
#define CONV_TOTAL 390480
// XZN/XZu are stored GATE-INTERLEAVED: index = elem*4 + gate (matches the
// MFMA chain's virtual-row order; one float4 per elem). aggr via atomicMin.
#define O_XZN   390528
#define O_XZU   (O_XZN + NNODE * ZM)
#define O_XZG   (O_XZU + NNODE * ZU)
#define O_XZA   (O_XZG + BG * ZG)
#define O_AGGR  (O_XZA + BG * ZA)
#define O_UPD   (O_AGGR + NNODE * HM)
#define WS_FLOATS (CV + O_UPD + NNODE * HU)

__device__ __forceinline__ float bf2f(u16 v) {
  return __uint_as_float(((u32)v) << 16);
}
__device__ __forceinline__ float rcp_(float x) { return __builtin_amdgcn_rcpf(x); }
__device__ __forceinline__ float sigf(float x) { return rcp_(1.0f + __expf(-x)); }
__device__ __forceinline__ float tanh_(float x) {
  float e = __expf(-2.0f * fabsf(x));
  float t = (1.0f - e) * rcp_(1.0f + e);
  return copysignf(t, x);
}
__device__ __forceinline__ float cvt(const void* p, int i, int flag) {
  return flag ? bf2f(((const u16*)p)[i]) : ((const float*)p)[i];
}
__device__ __forceinline__ u16 f2h(float a) {
  auto r = __builtin_amdgcn_cvt_pkrtz(a, a);
  u32 out;
  __builtin_memcpy(&out, &r, 4);
  return (u16)out;
}

// lgkmcnt-only barrier: LDS ordering without the vmcnt(0) drain that
// __syncthreads() emits. Global ops here are fire-and-forget stores/atomics
// (consumed by later kernels) and prefetch loads (vmcnt wait at first use).
#define BAR() asm volatile("s_waitcnt lgkmcnt(0)\n\ts_barrier" ::: "memory")

// ---------------------------------------------------------------------------
// K-1: runtime dtype detector (unchanged; fp32 was detected).
// ---------------------------------------------------------------------------
__global__ void k_detect(const u32* __restrict__ raw, int* __restrict__ flagp) {
  const int t = threadIdx.x;  // 64 threads (1 wave)
  int zlo = 0, hits = 0;
  for (int k = t; k < 256; k += 64) {
    u32 w = raw[k];
    if ((w & 0xFFFFu) == 0u) zlo++;
    u32 m = (w >> 8) & 0x7Fu;
    if (m >= 40u && m <= 70u) hits++;
  }
#pragma unroll
  for (int off = 32; off; off >>= 1) {
    zlo += __shfl_down(zlo, off, 64);
    hits += __shfl_down(hits, off, 64);
  }
  if (t == 0) *flagp = (zlo < 128 && hits >= 128) ? 1 : 0;
}

// ---------------------------------------------------------------------------
// K0: convert weights/biases (+ t=255 slices) to fp32 in workspace.
// ---------------------------------------------------------------------------
__global__ __launch_bounds__(256) void k_convert(
    const void* nodes, const void* gattr,
    const void* Wm, const void* Whm, const void* bm1, const void* bm2,
    const void* Wu, const void* Whu, const void* bu1, const void* bu2,
    const void* Wg, const void* Whg, const void* bg1, const void* bg2,
    const void* Wa, const void* Wha, const void* ba1, const void* ba2,
    const int* __restrict__ flagp, float* __restrict__ dst) {
  const int flag = *flagp;
  const int i = blockIdx.x * 256 + threadIdx.x;
  if (i >= CONV_TOTAL) return;
  float v;
  if (i < O_GA) {
    int n = i >> 6, f = i & 63;
    v = cvt(nodes, (n * TT + (TT - 1)) * FN + f, flag);
  } else if (i < O_WM) {
    int l = i - O_GA; int b = l >> 4, g = l & 15;
    v = cvt(gattr, (b * TT + (TT - 1)) * FG + g, flag);
  } else if (i < O_BM) {
    v = (i < O_WHM) ? cvt(Wm, i - O_WM, flag) : cvt(Whm, i - O_WHM, flag);
  } else if (i < O_WU) {
    int l = i - O_BM; v = cvt(bm1, l, flag) + cvt(bm2, l, flag);
  } else if (i < O_BU) {
    v = (i < O_WHU) ? cvt(Wu, i - O_WU, flag) : cvt(Whu, i - O_WHU, flag);
  } else if (i < O_WG) {
    int l = i - O_BU; v = cvt(bu1, l, flag) + cvt(bu2, l, flag);
  } else if (i < O_BG2) {
    v = (i < O_WHG) ? cvt(Wg, i - O_WG, flag) : cvt(Whg, i - O_WHG, flag);
  } else if (i < O_WA) {
    int l = i - O_BG2; v = cvt(bg1, l, flag) + cvt(bg2, l, flag);
  } else if (i < O_WHA) {
    v = cvt(Wa, i - O_WA, flag);
  } else if (i < O_BA) {
    v = cvt(Wha, i - O_WHA, flag);
  } else {
    int l = i - O_BA; v = cvt(ba1, l, flag) + cvt(ba2, l, flag);
  }
  dst[i] = v;
}

// ---------------------------------------------------------------------------
// K1: parallel precompute of input projections at t = T-1 (edge-msg proj per
// SOURCE NODE; faithful src==tgt==eidx quirk). XZN/XZu stored gate-
// interleaved: idx = (j&127)*4 + (j>>7) so each elem's 4 gates are one
// float4 (consumed by the MFMA chain's cell phase). Block n<NNODE also
// inits aggr[n] to +inf. Grid 2*NNODE + BG = 704 blocks.
// ---------------------------------------------------------------------------
__global__ __launch_bounds__(256) void k_pre(
    const float* __restrict__ cva,
    const int* __restrict__ num_nodes,
    float* __restrict__ XZN, float* __restrict__ XZu, float* __restrict__ XZg,
    u32* __restrict__ aggr) {
  const int blk = blockIdx.x, tid = threadIdx.x;
  __shared__ float xv[FN];
  __shared__ float gav[FG];
  __shared__ int sgr;
  const float* nodes255 = cva + O_NODES;
  const float* ga255 = cva + O_GA;

  if (blk < NNODE) {
    const int n = blk;
    if (tid < HM) aggr[(size_t)n * HM + tid] = 0x7f800000u;  // +inf bits
    if (tid == 0) {
      int g = 0, acc = 0;
      while (g < BG) { int c = num_nodes[g]; if (n < acc + c) break; acc += c; ++g; }
      if (g >= BG) g = BG - 1;
      sgr = g;
    }
    if (tid < FN) xv[tid] = nodes255[n * FN + tid];
    __syncthreads();
    if (tid < FG) gav[tid] = ga255[sgr * FG + tid];
    __syncthreads();
    for (int j = tid; j < ZM; j += 256) {
      const float* wr = cva + O_WM + j * DM;
      float acc = cva[O_BM + j];
#pragma unroll
      for (int d = 0; d < FN; ++d) acc += (wr[d] + wr[FN + d]) * xv[d];
#pragma unroll
      for (int d = 0; d < FG; ++d) acc += wr[2 * FN + d] * gav[d];
      XZN[(size_t)n * ZM + (j & 127) * 4 + (j >> 7)] = acc;
    }
  } else if (blk < 2 * NNODE) {
    const int n = blk - NNODE;
    if (tid == 0) {
      int g = 0, acc = 0;
      while (g < BG) { int c = num_nodes[g]; if (n < acc + c) break; acc += c; ++g; }
      if (g >= BG) g = BG - 1;
      sgr = g;
    }
    if (tid < FN) xv[tid] = nodes255[n * FN + tid];
    __syncthreads();
    if (tid < FG) gav[tid] = ga255[sgr * FG + tid];
    __syncthreads();
    for (int j = tid; j < ZU; j += 256) {
      const float* wr = cva + O_WU + j * DU;
      float acc = cva[O_BU + j];
#pragma unroll
      for (int d = 0; d < FN; ++d) acc += wr[d] * xv[d];
#pragma unroll
      for (int d = 0; d < FG; ++d) acc += wr[FN + HM + d] * gav[d];
      XZu[(size_t)n * ZU + (j & 127) * 4 + (j >> 7)] = acc;
    }
  } else {
    const int b = blk - 2 * NNODE;
    if (tid < FG) gav[tid] = ga255[b * FG + tid];
    __syncthreads();
    if (tid < ZG) {
      const float* wr = cva + O_WG + tid * DG;
      float acc = cva[O_BG2 + tid];
#pragma unroll
      for (int d = 0; d < FG; ++d) acc += wr[HU + d] * gav[d];
      XZg[(size_t)b * ZG + tid] = acc;
    }
  }
}

// ---------------------------------------------------------------------------
// K2/K4: LSTM chain on the MFMA pipe (round-14). 512 threads (8 waves).
//
// z = Whh(512x128) @ h(128) per step via v_mfma_f32_16x16x32_f16:
// 32 M-tiles x 4 K-chunks; wave w owns tiles 4w..4w+3 (16 mfma/wave/step).
// MFMA reads the fp16 weight fragments from AGPR/VGPR natively — the
// accvgpr-copy tax that capped every VALU formulation (rounds 0-13) is gone,
// and the MACs move off the VALU issue stream entirely.
//
// A packing uses GATE-INTERLEAVED virtual rows r' = elem*4 + gate. With the
// verified C/D layout (col=lane&15, row=(lane>>4)*4+reg — m89, dtype-indep),
// tile m's lane l accumulates rows 16m+(lane>>4)*4+reg = elem 4m+(lane>>4),
// gates reg 0..3: all 4 gates of one elem in one lane's f32x4 -> one b128
// LDS store. Assumed A layout: row=lane&15, k=(lane>>4)*8+j (standard CDNA
// mapping, mirrors verified D); B mirrored: col=lane&15, k=(lane>>4)*8+j.
// B trick: every lane reads the SAME h chunk -> B[k][col]=h[k] for all cols
// -> every D column equals z (no garbage lanes; col-0 lanes store).
//
// Cell phase: threads 0..127 (waves 0-1), one LSTM cell per thread:
// z float4 from LDS + xz float4 (gate-interleaved XZ) -> gates -> h ->
// fp16 h to LDS (+ output: ATOMIN atomicMin into aggr row idx[e], else
// store upd row e). GATHER: xz row index pipelined two steps ahead
// (round-12). Two lgkm barriers/step; hlds/zlds single-buffered (strict
// produce/consume phases).
// Tail reads: idx[STEPS]/idx[STEPS+1] = edge_indices row 1 (valid, <NNODE,
// unused). Non-gather rows to STEPS+1 read <=2 rows past XZ (workspace).
// ---------------------------------------------------------------------------
template <int STEPS, bool GATHER, bool ATOMIN>
__global__ __launch_bounds__(512, 2) void k_chain(
    const float* __restrict__ Whh, const float* __restrict__ XZ,
    const int* __restrict__ idx, float* __restrict__ hout) {
  const int t = threadIdx.x;       // 0..511
  const int lane = t & 63;
  const int wv = t >> 6;           // wave 0..7
  const bool iscell = (t < 128);
  __shared__ __align__(16) u16 hlds[136];    // fp16 h[128] + pad
  __shared__ __align__(16) float zlds[512];  // z in virtual order elem*4+p

  // A fragments: 4 tiles x 4 k-chunks, packed fp16.
  h8 wfrag[16];
  {
    const int vr = lane & 15;           // row-in-tile
    const int kb = (lane >> 4) * 8;     // k-base within chunk
#pragma unroll
    for (int mm = 0; mm < 4; ++mm) {
      const int m = wv * 4 + mm;
      const int vrow = 16 * m + vr;     // virtual row = elem*4 + gate
      const int elem = vrow >> 2;
      const int p = vrow & 3;
      const float* row = Whh + (size_t)(p * 128 + elem) * 128;
#pragma unroll
      for (int c = 0; c < 4; ++c) {
        float4 lo = *(const float4*)(row + 32 * c + kb);
        float4 hi = *(const float4*)(row + 32 * c + kb + 4);
        h8 f;
        f[0] = (__fp16)lo.x; f[1] = (__fp16)lo.y;
        f[2] = (__fp16)lo.z; f[3] = (__fp16)lo.w;
        f[4] = (__fp16)hi.x; f[5] = (__fp16)hi.y;
        f[6] = (__fp16)hi.z; f[7] = (__fp16)hi.w;
        wfrag[mm * 4 + c] = f;
      }
    }
  }

  float cst = 0.0f;
  int crow = 0, nrow = 1;
  f32x4 xz = {0.0f, 0.0f, 0.0f, 0.0f};
  if (iscell) {
    crow = GATHER ? idx[0] : 0;
    nrow = GATHER ? idx[1] : 1;
    xz = *(const f32x4*)(XZ + (size_t)crow * 512 + t * 4);
  }
  if (t < 136) hlds[t] = 0;  // h = 0 (fp16 zero)
  BAR();

  for (int e = 0; e < STEPS; ++e) {
    // ---- MFMA phase (all 8 waves) ----
    h8 bf[4];
#pragma unroll
    for (int c = 0; c < 4; ++c) {
      uint4 v = *(const uint4*)((const char*)hlds + 64 * c + ((lane >> 4) & 3) * 16);
      __builtin_memcpy(&bf[c], &v, 16);
    }
    f32x4 d0 = {0.0f, 0.0f, 0.0f, 0.0f};
    f32x4 d1 = d0, d2 = d0, d3 = d0;
#pragma unroll
    for (int c = 0; c < 4; ++c) {
      d0 = __builtin_amdgcn_mfma_f32_16x16x32_f16(wfrag[0 * 4 + c], bf[c], d0, 0, 0, 0);
      d1 = __builtin_amdgcn_mfma_f32_16x16x32_f16(wfrag[1 * 4 + c], bf[c], d1, 0, 0, 0);
      d2 = __builtin_amdgcn_mfma_f32_16x16x32_f16(wfrag[2 * 4 + c], bf[c], d2, 0, 0, 0);
      d3 = __builtin_amdgcn_mfma_f32_16x16x32_f16(wfrag[3 * 4 + c], bf[c], d3, 0, 0, 0);
    }
    if ((lane & 15) == 0) {  // col-0 lanes hold z rows (all cols identical)
      const int rb = (lane >> 4) * 4;
      *(f32x4*)&zlds[16 * (wv * 4 + 0) + rb] = d0;
      *(f32x4*)&zlds[16 * (wv * 4 + 1) + rb] = d1;
      *(f32x4*)&zlds[16 * (wv * 4 + 2) + rb] = d2;
      *(f32x4*)&zlds[16 * (wv * 4 + 3) + rb] = d3;
    }
    BAR();  // z visible
    // ---- cell phase (waves 0-1; one elem per thread) ----
    if (iscell) {
      f32x4 z = *(const f32x4*)&zlds[t * 4];
      float zi = z[0] + xz[0], zf = z[1] + xz[1];
      float zg = z[2] + xz[2], zo = z[3] + xz[3];
      // prefetch next xz with the already-resident row; refill nrow after
      int crow_next = nrow;
      f32x4 xzn = *(const f32x4*)(XZ + (size_t)nrow * 512 + t * 4);
      nrow = GATHER ? idx[e + 2] : (e + 2);
      float si = sigf(zi), sf = sigf(zf), so = sigf(zo);
      float tg = tanh_(zg);
      cst = sf * cst + si * tg;
      float h = so * tanh_(cst);
      hlds[t] = f2h(h);
      float hr = fmaxf(h, 0.0f);
      if (ATOMIN) {
        atomicMin((u32*)&hout[(size_t)crow * HM + t], __float_as_uint(hr));
      } else {
        hout[(size_t)e * 128 + t] = hr;
      }
      crow = crow_next;
      xz = xzn;
    }
    BAR();  // h visible
  }
}

// ---------------------------------------------------------------------------
// K3: XZu[n] += Wih_u[:,64:192] @ aggr[n]   (320 blocks; gate-interleaved
// XZu indexing to match the chain).
// ---------------------------------------------------------------------------
__global__ __launch_bounds__(256) void k_aggproj(
    const float* __restrict__ cva, const float* __restrict__ aggr,
    float* __restrict__ XZu) {
  const int n = blockIdx.x, tid = threadIdx.x;
  __shared__ float av[HM];
  if (tid < HM) av[tid] = aggr[(size_t)n * HM + tid];
  __syncthreads();
  for (int j = tid; j < ZU; j += 256) {
    const float* wr = cva + O_WU + j * DU + FN;
    float acc = 0.0f;
#pragma unroll
    for (int k = 0; k < HM; ++k) acc += wr[k] * av[k];
    XZu[(size_t)n * ZU + (j & 127) * 4 + (j >> 7)] += acc;
  }
}

// ---------------------------------------------------------------------------
// K5: fused (aggB computed in-block, never global).
// blocks [0,64): aggB[b] = segmin(upd) -> XZg[b] += Wih_g[:,0:128] @ aggB[b]
// blocks [64,128): chosen[b] -> XZa[b] = Wih_a[:,0:128] @ chosen[b] + biases
// ---------------------------------------------------------------------------
__global__ __launch_bounds__(256) void k_gproj(
    const float* __restrict__ cva, const float* __restrict__ upd,
    const int* __restrict__ bidx, const int* __restrict__ who,
    float* __restrict__ XZg, float* __restrict__ XZa) {
  const int blk = blockIdx.x, tid = threadIdx.x;
  __shared__ float buf[HU];
  __shared__ int satbw;
  if (blk < BG) {
    const int b = blk;
    if (tid < HU) {
      float m = __uint_as_float(0x7f800000u);
      for (int n = 0; n < NNODE; ++n) {
        if (bidx[n] == b) m = fminf(m, upd[(size_t)n * HU + tid]);
      }
      buf[tid] = m;
    }
    __syncthreads();
    if (tid < ZG) {
      const float* wr = cva + O_WG + tid * DG;
      float acc = 0.0f;
#pragma unroll
      for (int k = 0; k < HU; ++k) acc += wr[k] * buf[k];
      XZg[(size_t)b * ZG + tid] += acc;
    }
  } else {
    const int b = blk - BG;
    const int whoB = who[b];
    if (tid == 0) {
      int off = 0;
      for (int i = 0; i < NNODE; ++i) off += (bidx[i] < b) ? 1 : 0;
      const int adj = (whoB == 3) ? 2 : whoB;
      satbw = (b == 0) ? who[0] : (adj + off);
    }
    if (whoB == 3) {
      if (tid < HU) {
        float m = __uint_as_float(0x7f800000u);
        for (int n = 0; n < NNODE; ++n) {
          if (bidx[n] == b) m = fminf(m, upd[(size_t)n * HU + tid]);
        }
        buf[tid] = m;
      }
      __syncthreads();
    } else {
      __syncthreads();
      if (tid < HU) buf[tid] = upd[(size_t)satbw * HU + tid];
      __syncthreads();
    }
    if (tid < ZA) {
      const float* wr = cva + O_WA + tid * DA;
      float acc = cva[O_BA + tid];
#pragma unroll
      for (int k = 0; k < HU; ++k) acc += wr[k] * buf[k];
      XZa[(size_t)b * ZA + tid] = acc;
    }
  }
}

// ---------------------------------------------------------------------------
// K6: group LSTM chain + action chain, software-pipelined (round-13): group
// step b and action step b-1 share one barrier pair.
// ---------------------------------------------------------------------------
__global__ __launch_bounds__(256, 2) void k_final(
    const float* __restrict__ cva, const float* __restrict__ XZg,
    const float* __restrict__ XZa, float* __restrict__ out) {
  const int j = threadIdx.x;
  __shared__ __align__(16) float hg[HG];
  __shared__ float zsg[ZG];
  __shared__ float grp[BG * HG];
  __shared__ float za[ZA];
  __shared__ float haL[HA];
  __shared__ float res[BG * HA];

  float wg[HG];
  {
    const float* wr = cva + O_WHG + j * HG;
#pragma unroll
    for (int k = 0; k < HG; ++k) wg[k] = wr[k];
  }
  float wa2[HG];
  float wha[HA];
  if (j < ZA) {
    const float* wr2 = cva + O_WA + j * DA + HU;
#pragma unroll
    for (int k = 0; k < HG; ++k) wa2[k] = wr2[k];
#pragma unroll
    for (int k = 0; k < HA; ++k) wha[k] = cva[O_WHA + j * HA + k];
  }
  if (j < HG) hg[j] = 0.0f;
  if (j < HA) haL[j] = 0.0f;
  float cg = 0.0f, ca = 0.0f;
  __syncthreads();

  for (int b = 0; b <= BG; ++b) {
    if (b < BG) {
      float acc = XZg[(size_t)b * ZG + j];
#pragma unroll
      for (int k = 0; k < HG; ++k) acc += wg[k] * hg[k];
      zsg[j] = acc;
    }
    if (b > 0 && j < ZA) {
      float acc = XZa[(size_t)(b - 1) * ZA + j];
#pragma unroll
      for (int k = 0; k < HG; ++k) acc += wa2[k] * grp[(b - 1) * HG + k];
#pragma unroll
      for (int k = 0; k < HA; ++k) acc += wha[k] * haL[k];
      za[j] = acc;
    }
    __syncthreads();
    if (b < BG && j < HG) {
      float zi = zsg[j], zf = zsg[HG + j], zg = zsg[2 * HG + j], zo = zsg[3 * HG + j];
      cg = sigf(zf) * cg + sigf(zi) * tanh_(zg);
      float h = sigf(zo) * tanh_(cg);
      hg[j] = h;
      grp[b * HG + j] = fmaxf(h, 0.0f);
    }
    if (b > 0 && j < HA) {
      float zi = za[j], zf = za[HA + j], zg = za[2 * HA + j], zo = za[3 * HA + j];
      ca = sigf(zf) * ca + sigf(zi) * tanh_(zg);
      float h = sigf(zo) * tanh_(ca);
      haL[j] = h;
      res[(b - 1) * HA + j] = h;
    }
    __syncthreads();
  }

  if (j < BG) {
    float x0 = res[j * 4 + 0], x1 = res[j * 4 + 1];
    float x2 = res[j * 4 + 2], x3 = res[j * 4 + 3];
    float m = fmaxf(fmaxf(x0, x1), fmaxf(x2, x3));
    float e0 = __expf(x0 - m), e1 = __expf(x1 - m);
    float e2 = __expf(x2 - m), e3 = __expf(x3 - m);
    float s = e0 + e1 + e2 + e3;
    out[j * 4 + 0] = e0 / s;
    out[j * 4 + 1] = e1 / s;
    out[j * 4 + 2] = e2 / s;
    out[j * 4 + 3] = e3 / s;
  }
}

__global__ void k_zero(float* out) { out[threadIdx.x] = 0.0f; }

extern "C" void kernel_launch(void* const* d_in, const int* in_sizes, int n_in,
                              void* d_out, int out_size, void* d_ws, size_t ws_size,
                              hipStream_t stream) {
  const void* nodes = d_in[0];
  const void* gattr = d_in[1];
  const int* eidx  = (const int*)d_in[2];
  const int* nn    = (const int*)d_in[3];
  const int* ne    = (const int*)d_in[4];
  const int* bidx  = (const int*)d_in[5];
  const int* who   = (const int*)d_in[6];
  (void)ne;

  if (ws_size < (size_t)WS_FLOATS * 4) {
    k_zero<<<1, 256, 0, stream>>>((float*)d_out);
    return;
  }

  float* ws = (float*)d_ws;
  int* flagp = (int*)d_ws;
  float* cva = ws + CV;
  float* XZN = cva + O_XZN;
  float* XZu = cva + O_XZU;
  float* XZg = cva + O_XZG;
  float* XZa = cva + O_XZA;
  float* aggr = cva + O_AGGR;
  float* upd = cva + O_UPD;

  k_detect<<<1, 64, 0, stream>>>((const u32*)nodes, flagp);
  k_convert<<<(CONV_TOTAL + 255) / 256, 256, 0, stream>>>(
      nodes, gattr,
      d_in[7], d_in[8], d_in[9], d_in[10],
      d_in[11], d_in[12], d_in[13], d_in[14],
      d_in[15], d_in[16], d_in[17], d_in[18],
      d_in[19], d_in[20], d_in[21], d_in[22],
      flagp, cva);
  k_pre<<<2 * NNODE + BG, 256, 0, stream>>>(cva, nn, XZN, XZu, XZg, (u32*)aggr);
  k_chain<NEDGE, true, true><<<1, 512, 0, stream>>>(cva + O_WHM, XZN, eidx, aggr);
  k_aggproj<<<NNODE, 256, 0, stream>>>(cva, aggr, XZu);
  k_chain<NNODE, false, false><<<1, 512, 0, stream>>>(cva + O_WHU, XZu, nullptr, upd);
  k_gproj<<<2 * BG, 256, 0, stream>>>(cva, upd, bidx, who, XZg, XZa);
  k_final<<<1, 256, 0, stream>>>(cva, XZg, XZa, (float*)d_out);
}